// Round 17
// baseline (720.346 us; speedup 1.0000x reference)
//
#include <hip/hip_runtime.h>
#include <math.h>

#define NTOK 16384
#define DDIM 2048
#define NEXP 64
#define RRANK 128
#define CAP 640  // ceil(1.25 * 32768 / 64)

typedef __attribute__((ext_vector_type(8))) short bf16x8;
typedef __attribute__((ext_vector_type(4))) float f32x4;
typedef __attribute__((address_space(1))) const unsigned int gu32_t;
typedef __attribute__((address_space(3))) unsigned int lu32_t;

__device__ __forceinline__ void gload16(const void* g, void* l) {
  __builtin_amdgcn_global_load_lds((gu32_t*)g, (lu32_t*)l, 16, 0, 0);
}

__device__ __forceinline__ float silu_f(float v) {
  return v / (1.f + expf(-v));
}

__device__ __forceinline__ unsigned short f2bf(float f) {
  unsigned int u = __float_as_uint(f);
  unsigned int r = (u + 0x7fffu + ((u >> 16) & 1u)) >> 16;
  return (unsigned short)r;
}

__device__ __forceinline__ float bf2f(unsigned short u) {
  return __uint_as_float(((unsigned int)u) << 16);
}

__device__ __forceinline__ int swz256(int d) {  // XOR-swizzle for 256B-row tiles
  return d ^ (((d >> 8) & 7) << 4);
}

// ------- fp32 -> bf16 bulk convert (all 4 tensors) + val zeroing -----------
__global__ __launch_bounds__(256) void cvt_all_kernel(
    const float* __restrict__ x, const float* __restrict__ We,
    const float* __restrict__ U, const float* __restrict__ V,
    unsigned short* __restrict__ xb, unsigned short* __restrict__ Web,
    unsigned short* __restrict__ Ub, unsigned short* __restrict__ Vb,
    int* __restrict__ val)
{
  const int S0 = NTOK * DDIM / 4;
  const int S1 = DDIM * DDIM / 4;
  const int S2 = NEXP * RRANK * DDIM / 4;
  const int total = S0 + S1 + 2 * S2;
  const int g0 = blockIdx.x * 256 + threadIdx.x;
  if (g0 < NTOK * 2) val[g0] = 0;   // grid 2048*256 >= 32768
  int i = g0;
  const int stride = gridDim.x * 256;
  for (; i < total; i += stride) {
    const float* in; unsigned short* out; int j;
    if (i < S0) { in = x; out = xb; j = i; }
    else if (i < S0 + S1) { in = We; out = Web; j = i - S0; }
    else if (i < S0 + S1 + S2) { in = U; out = Ub; j = i - S0 - S1; }
    else { in = V; out = Vb; j = i - S0 - S1 - S2; }
    const float4 v = ((const float4*)in)[j];
    ushort4 o;
    o.x = f2bf(v.x); o.y = f2bf(v.y); o.z = f2bf(v.z); o.w = f2bf(v.w);
    ((ushort4*)out)[j] = o;
  }
}

// ---- encoder GEMM: 256x256 tile, BK=64, 8 waves, dbuf LDS, counted vmcnt,
//      split-phase: stage 6/8 loads after phase-A (their LDS targets dead) ---
__global__ __launch_bounds__(512, 2) void enc_mfma5(
    const unsigned short* __restrict__ xb, const unsigned short* __restrict__ Web,
    const float* __restrict__ be, unsigned short* __restrict__ encbf)
{
  __shared__ unsigned short LDS[65536];  // A0|A1|B0|B1, 32KB each (128KB)
  const int tid = threadIdx.x;
  const int lane = tid & 63, wid = tid >> 6;
  const int wr = wid >> 2, wc = wid & 3;     // 2M x 4N wave grid
  const int fr = lane & 15, fq = lane >> 4;
  const int bid = blockIdx.x;
  const int wg = (bid & 7) * 64 + (bid >> 3);  // bijective XCD swizzle (512%8==0)
  const int n0 = (wg & 7) * 256, m0 = (wg >> 3) * 256;

  const unsigned short* asb[4];
  const unsigned short* bsb[4];
  int d4[4];
#pragma unroll
  for (int is = 0; is < 4; ++is) {
    const int doff = is * 8192 + tid * 16;   // bytes within 32KB tile
    const int r = doff >> 7;                 // 128B rows (64 bf16): is*64 + tid/8
    const int cs = ((doff >> 4) & 7) ^ (r & 7);
    asb[is] = xb + (size_t)(m0 + r) * DDIM + cs * 8;
    bsb[is] = Web + (size_t)(n0 + r) * DDIM + cs * 8;
    d4[is] = doff;
  }

  auto STAGE_A = [&](int buf, int kb, int is) {
    gload16(asb[is] + kb, (char*)(LDS + buf * 16384) + d4[is]);
  };
  auto STAGE_B = [&](int buf, int kb, int is) {
    gload16(bsb[is] + kb, (char*)(LDS + 32768 + buf * 16384) + d4[is]);
  };

  f32x4 acc[8][4];
#pragma unroll
  for (int m = 0; m < 8; ++m)
#pragma unroll
    for (int n = 0; n < 4; ++n) acc[m][n] = (f32x4){0.f, 0.f, 0.f, 0.f};

  // prologue: tiles 0 and 1
#pragma unroll
  for (int is = 0; is < 4; ++is) { STAGE_A(0, 0, is); STAGE_B(0, 0, is); }
#pragma unroll
  for (int is = 0; is < 4; ++is) { STAGE_A(1, 64, is); STAGE_B(1, 64, is); }
  asm volatile("s_waitcnt vmcnt(8)" ::: "memory");  // tile0 landed; tile1 in flight
  __builtin_amdgcn_s_barrier();
  asm volatile("" ::: "memory");

#pragma unroll 1
  for (int t = 0; t < 32; ++t) {
    const int cur = t & 1;
    const int kb2 = (t + 2) * 64;
    const unsigned short* Ab = LDS + cur * 16384;
    const unsigned short* Bb = LDS + 32768 + cur * 16384;

    // ---- phase A: all B-frags + A-frags mh=0 (rows: wr=0->is0, wr=1->is2) --
    bf16x8 bfv[4][2];
#pragma unroll
    for (int n = 0; n < 4; ++n) {
      const int row = wc * 64 + n * 16 + fr;
#pragma unroll
      for (int kk = 0; kk < 2; ++kk)
        bfv[n][kk] = *(const bf16x8*)((const char*)Bb +
                      row * 128 + (((kk * 4 + fq) ^ (row & 7)) << 4));
    }
    {
      bf16x8 af[4][2];
#pragma unroll
      for (int m = 0; m < 4; ++m) {
        const int row = wr * 128 + m * 16 + fr;
#pragma unroll
        for (int kk = 0; kk < 2; ++kk)
          af[m][kk] = *(const bf16x8*)((const char*)Ab +
                       row * 128 + (((kk * 4 + fq) ^ (row & 7)) << 4));
      }
      __builtin_amdgcn_s_setprio(1);
#pragma unroll
      for (int m = 0; m < 4; ++m)
#pragma unroll
        for (int n = 0; n < 4; ++n)
#pragma unroll
          for (int kk = 0; kk < 2; ++kk)
            acc[m][n] = __builtin_amdgcn_mfma_f32_16x16x32_bf16(
                af[m][kk], bfv[n][kk], acc[m][n], 0, 0, 0);
      __builtin_amdgcn_s_setprio(0);
    }

    asm volatile("s_waitcnt lgkmcnt(0)" ::: "memory");  // phase-A reads retired
    __builtin_amdgcn_s_barrier();                       // b1: is0,is2,B dead
    if (t < 30) {  // stage 6 loads into dead regions; overlap with phase B
      STAGE_A(cur, kb2, 0);
      STAGE_A(cur, kb2, 2);
#pragma unroll
      for (int is = 0; is < 4; ++is) STAGE_B(cur, kb2, is);
    }

    // ---- phase B: A-frags mh=1 (rows: wr=0->is1, wr=1->is3) ---------------
    {
      bf16x8 af[4][2];
#pragma unroll
      for (int m = 0; m < 4; ++m) {
        const int row = wr * 128 + 64 + m * 16 + fr;
#pragma unroll
        for (int kk = 0; kk < 2; ++kk)
          af[m][kk] = *(const bf16x8*)((const char*)Ab +
                       row * 128 + (((kk * 4 + fq) ^ (row & 7)) << 4));
      }
      __builtin_amdgcn_s_setprio(1);
#pragma unroll
      for (int m = 0; m < 4; ++m)
#pragma unroll
        for (int n = 0; n < 4; ++n)
#pragma unroll
          for (int kk = 0; kk < 2; ++kk)
            acc[4 + m][n] = __builtin_amdgcn_mfma_f32_16x16x32_bf16(
                af[m][kk], bfv[n][kk], acc[4 + m][n], 0, 0, 0);
      __builtin_amdgcn_s_setprio(0);
    }

    asm volatile("s_waitcnt lgkmcnt(0)" ::: "memory");  // phase-B reads retired
    __builtin_amdgcn_s_barrier();                       // b2: is1,is3 dead
    if (t < 30) {
      STAGE_A(cur, kb2, 1);
      STAGE_A(cur, kb2, 3);
      asm volatile("s_waitcnt vmcnt(8)" ::: "memory");  // tile t+1 fully landed
    } else {
      asm volatile("s_waitcnt vmcnt(0)" ::: "memory");  // epilogue drain
    }
    __builtin_amdgcn_s_barrier();                       // b3: next buffer ready
    asm volatile("" ::: "memory");
  }

  float bias[4];
#pragma unroll
  for (int n = 0; n < 4; ++n) bias[n] = be[n0 + wc * 64 + n * 16 + fr];
#pragma unroll
  for (int m = 0; m < 8; ++m) {
#pragma unroll
    for (int j = 0; j < 4; ++j) {
      const int row = m0 + wr * 128 + m * 16 + fq * 4 + j;
      unsigned short* ob = encbf + (size_t)row * DDIM + n0 + wc * 64 + fr;
#pragma unroll
      for (int n = 0; n < 4; ++n)
        ob[n * 16] = f2bf(acc[m][n][j] + bias[n]);
    }
  }
}

// ------- G partials (fp64): Gpart[oc][e][d] over o-chunk oc ----------------
__global__ __launch_bounds__(256) void gmat_part_kernel(
    const float* __restrict__ We, const float* __restrict__ Wg,
    double* __restrict__ Gpart)
{
  __shared__ float As[64][68];  // [o][d]
  __shared__ float Bs[64][68];  // [o][e]
  const int tid = threadIdx.x;
  const int d0 = blockIdx.x * 64;
  const int oc = blockIdx.y;
  const int tx = tid & 15, ty = tid >> 4;
  const int row = tid >> 2, p = (tid & 3) * 16;

  double acc[4][4];
#pragma unroll
  for (int j = 0; j < 4; ++j)
#pragma unroll
    for (int i = 0; i < 4; ++i) acc[j][i] = 0.0;

  for (int o0 = oc * 256; o0 < oc * 256 + 256; o0 += 64) {
    float4 wv[4], gv[4];
#pragma unroll
    for (int q = 0; q < 4; ++q) {
      wv[q] = *(const float4*)(We + (size_t)(o0 + row) * DDIM + d0 + p + q * 4);
      gv[q] = *(const float4*)(Wg + (size_t)row * DDIM + o0 + p + q * 4);
    }
    __syncthreads();
#pragma unroll
    for (int q = 0; q < 4; ++q) {
      const int c = p + q * 4;
      As[row][c + 0] = wv[q].x; As[row][c + 1] = wv[q].y;
      As[row][c + 2] = wv[q].z; As[row][c + 3] = wv[q].w;
      Bs[c + 0][row] = gv[q].x; Bs[c + 1][row] = gv[q].y;
      Bs[c + 2][row] = gv[q].z; Bs[c + 3][row] = gv[q].w;
    }
    __syncthreads();
#pragma unroll 8
    for (int oo = 0; oo < 64; ++oo) {
      double a[4], b[4];
#pragma unroll
      for (int j = 0; j < 4; ++j) a[j] = (double)As[oo][ty * 4 + j];
#pragma unroll
      for (int i = 0; i < 4; ++i) b[i] = (double)Bs[oo][tx * 4 + i];
#pragma unroll
      for (int j = 0; j < 4; ++j)
#pragma unroll
        for (int i = 0; i < 4; ++i)
          acc[j][i] = fma(a[j], b[i], acc[j][i]);
    }
    __syncthreads();
  }
#pragma unroll
  for (int j = 0; j < 4; ++j)
#pragma unroll
    for (int i = 0; i < 4; ++i) {
      const int d = d0 + ty * 4 + j, e = tx * 4 + i;
      Gpart[(size_t)oc * (DDIM * NEXP) + (size_t)e * DDIM + d] = acc[j][i];
    }
}

// ------- reduce partials -> Gt (fp64) + G_bf (bf16) ------------------------
__global__ __launch_bounds__(256) void greduce_kernel(
    const double* __restrict__ Gpart, double* __restrict__ Gt,
    unsigned short* __restrict__ Gbf)
{
  const int idx = blockIdx.x * 256 + threadIdx.x;  // 131072 total
  double s = 0.0;
#pragma unroll
  for (int oc = 0; oc < 8; ++oc)
    s += Gpart[(size_t)oc * (DDIM * NEXP) + idx];
  Gt[idx] = s;
  Gbf[idx] = f2bf((float)s);
}

// ---------------- c[e] = be . Wg[e]  (fp64) --------------------------------
__global__ __launch_bounds__(256) void bias_c_kernel(
    const float* __restrict__ be, const float* __restrict__ Wg,
    double* __restrict__ c64)
{
  const int e = blockIdx.x;
  const int tid = threadIdx.x;
  double s = 0.0;
  for (int o = tid; o < DDIM; o += 256)
    s += (double)be[o] * (double)Wg[(size_t)e * DDIM + o];
  __shared__ double red[256];
  red[tid] = s;
  __syncthreads();
  for (int st = 128; st > 0; st >>= 1) {
    if (tid < st) red[tid] += red[tid + st];
    __syncthreads();
  }
  if (tid == 0) c64[e] = red[0];
}

// ---- approx logits (bf16 MFMA) + per-token top-8; 64 tok/block, grid 256 --
__global__ __launch_bounds__(256) void logits_topc_kernel(
    const unsigned short* __restrict__ xb, const unsigned short* __restrict__ Gbf,
    const double* __restrict__ c64, int* __restrict__ cand8)
{
  __shared__ unsigned short At[64 * 64];  // 8 KB: tokens x k (swizzled)
  __shared__ unsigned short Bt[64 * 64];  // 8 KB: experts x k (swizzled)
  __shared__ float Ls[64][64];            // 16 KB logits
  const int tid = threadIdx.x;
  const int lane = tid & 63, wid = tid >> 6;
  const int fr = lane & 15, fq = lane >> 4;
  const int t0 = blockIdx.x * 64;  // grid 256

  // staging: 2 issues per matrix per tile; linear LDS dest, swizzled source
  const unsigned short* asrc[2];
  const unsigned short* bsrc[2];
  int d2[2];
#pragma unroll
  for (int is = 0; is < 2; ++is) {
    const int doff = is * 4096 + tid * 16;   // bytes within 8KB tile
    const int r = doff >> 7;                 // 128B rows (64 bf16)
    const int cs = ((doff >> 4) & 7) ^ (r & 7);
    asrc[is] = xb + (size_t)(t0 + r) * DDIM + cs * 8;
    bsrc[is] = Gbf + (size_t)r * DDIM + cs * 8;
    d2[is] = doff;
  }

  f32x4 acc[4];
#pragma unroll
  for (int n = 0; n < 4; ++n) acc[n] = (f32x4){0.f, 0.f, 0.f, 0.f};

  for (int kb = 0; kb < DDIM; kb += 64) {
    __syncthreads();
#pragma unroll
    for (int is = 0; is < 2; ++is) {
      gload16(asrc[is] + kb, (char*)At + d2[is]);
      gload16(bsrc[is] + kb, (char*)Bt + d2[is]);
    }
    __syncthreads();
    const int arow = wid * 16 + fr;
    bf16x8 af[2], bfr[4][2];
#pragma unroll
    for (int kk = 0; kk < 2; ++kk)
      af[kk] = *(const bf16x8*)((const char*)At +
                arow * 128 + (((kk * 4 + fq) ^ (arow & 7)) << 4));
#pragma unroll
    for (int n = 0; n < 4; ++n) {
      const int brow = n * 16 + fr;
#pragma unroll
      for (int kk = 0; kk < 2; ++kk)
        bfr[n][kk] = *(const bf16x8*)((const char*)Bt +
                      brow * 128 + (((kk * 4 + fq) ^ (brow & 7)) << 4));
    }
#pragma unroll
    for (int n = 0; n < 4; ++n)
#pragma unroll
      for (int kk = 0; kk < 2; ++kk)
        acc[n] = __builtin_amdgcn_mfma_f32_16x16x32_bf16(af[kk], bfr[n][kk], acc[n], 0, 0, 0);
  }

#pragma unroll
  for (int j = 0; j < 4; ++j) {
    const int row = wid * 16 + fq * 4 + j;
#pragma unroll
    for (int n = 0; n < 4; ++n)
      Ls[row][n * 16 + fr] = acc[n][j];
  }
  __syncthreads();

  if (tid < 64) {
    float v8[8];
    int i8[8];
#pragma unroll
    for (int c = 0; c < 8; ++c) { v8[c] = -INFINITY; i8[c] = 0; }
    for (int e = 0; e < NEXP; ++e) {
      const float v = Ls[tid][e] + (float)c64[e];
      if (v > v8[7]) {
        int p = 7;
        while (p > 0 && v > v8[p - 1]) { v8[p] = v8[p - 1]; i8[p] = i8[p - 1]; --p; }
        v8[p] = v; i8[p] = e;
      }
    }
    int* cp = cand8 + (size_t)(t0 + tid) * 8;
#pragma unroll
    for (int c = 0; c < 8; ++c) cp[c] = i8[c];
  }
}

// ---- exact fp64 refine of 8 candidates: wave-per-token, no barriers -------
__global__ __launch_bounds__(256) void refine_kernel(
    const float* __restrict__ x, const double* __restrict__ Gt,
    const double* __restrict__ c64, const int* __restrict__ cand8,
    int* __restrict__ topk, float* __restrict__ wkf)
{
  const int tid = threadIdx.x;
  const int lane = tid & 63, w = tid >> 6;
  const int t = blockIdx.x * 4 + w;  // grid 4096, 4 tokens/block

  // x row in registers: lane holds d = 256q + 4*lane + j (j=0..3)
  float xr[32];
  const float4* xp = (const float4*)(x + (size_t)t * DDIM);
#pragma unroll
  for (int q = 0; q < 8; ++q) {
    const float4 v = xp[q * 64 + lane];
    xr[q * 4 + 0] = v.x; xr[q * 4 + 1] = v.y;
    xr[q * 4 + 2] = v.z; xr[q * 4 + 3] = v.w;
  }

  int myc[8];
#pragma unroll
  for (int c = 0; c < 8; ++c) myc[c] = cand8[(size_t)t * 8 + c];

  double s[8];
#pragma unroll
  for (int c = 0; c < 8; ++c) {
    const double* g = Gt + (size_t)myc[c] * DDIM;
    double acc = 0.0;
#pragma unroll
    for (int q = 0; q < 8; ++q) {
      const int d = q * 256 + lane * 4;
      const double2 g0 = *(const double2*)(g + d);
      const double2 g1 = *(const double2*)(g + d + 2);
      acc = fma((double)xr[q * 4 + 0], g0.x, acc);
      acc = fma((double)xr[q * 4 + 1], g0.y, acc);
      acc = fma((double)xr[q * 4 + 2], g1.x, acc);
      acc = fma((double)xr[q * 4 + 3], g1.y, acc);
    }
#pragma unroll
    for (int off = 32; off > 0; off >>= 1)
      acc += __shfl_xor(acc, off);
    s[c] = acc + c64[myc[c]];
  }

  if (lane == 0) {
    double v1 = -1e300, v2 = -1e300;
    int i1 = 0, i2 = 0;
#pragma unroll
    for (int c = 0; c < 8; ++c) {
      const double v = s[c];
      if (v > v1) { v2 = v1; i2 = i1; v1 = v; i1 = myc[c]; }
      else if (v > v2) { v2 = v; i2 = myc[c]; }
    }
    const double e2 = exp(v2 - v1);
    const double sm = 1.0 + e2 + 1e-12;
    topk[2 * t] = i1; topk[2 * t + 1] = i2;
    wkf[2 * t] = (float)(1.0 / sm);
    wkf[2 * t + 1] = (float)(e2 / sm);
  }
}

// ------- deterministic capacity routing: 2-pass wave-local scan ------------
__global__ __launch_bounds__(256) void route_kernel(
    const int* __restrict__ topk, const float* __restrict__ wkf,
    int* __restrict__ slots /* [NEXP][CAP] */, int* __restrict__ counts_eff,
    int* __restrict__ val /* [N] pre-zeroed by cvt_all */)
{
  const int e = blockIdx.x;
  const int tid = threadIdx.x;
  const int lane = tid & 63, wave = tid >> 6;
  const int base0 = wave * 8192;  // each wave owns a contiguous range
  __shared__ int wcnt[4];

  // pass 1: count matches in this wave's range (no barriers)
  int cnt = 0;
  for (int c = 0; c < 8192; c += 64) {
    const int a = base0 + c + lane;
    const bool match = (topk[a] == e) && (wkf[a] > 1e-12f);
    cnt += (int)__popcll(__ballot(match));
  }
  if (lane == 0) wcnt[wave] = cnt;
  __syncthreads();

  int run = 0;
  for (int w = 0; w < 4; ++w)
    if (w < wave) run += wcnt[w];
  const int total = wcnt[0] + wcnt[1] + wcnt[2] + wcnt[3];

  // pass 2: assign ranks in token order
  for (int c = 0; c < 8192; c += 64) {
    const int a = base0 + c + lane;
    const bool match = (topk[a] == e) && (wkf[a] > 1e-12f);
    const unsigned long long bal = __ballot(match);
    const int rank = run + (int)__popcll(bal & ((1ull << lane) - 1ull));
    if (match && rank < CAP) {
      slots[e * CAP + rank] = a;
      val[a] = 1;
    }
    run += (int)__popcll(bal);
  }
  if (tid == 0) counts_eff[e] = (total < CAP) ? total : CAP;
}

// ----- fused expert: phase 1 now dbuf + counted vmcnt (enc-style);
//       phase 2 unchanged (64-row V halves, dbuf + counted vmcnt)
__global__ __launch_bounds__(256) void expert_fused(
    const unsigned short* __restrict__ encbf, const unsigned short* __restrict__ Ub,
    const unsigned short* __restrict__ Vb, const float* __restrict__ gamma,
    const int* __restrict__ counts_eff, const int* __restrict__ slots,
    const float* __restrict__ wkf, unsigned short* __restrict__ Dbuf)
{
  const int lin = blockIdx.x;                   // 640 wgs
  const int wg = (lin & 7) * 80 + (lin >> 3);   // XCD swizzle: expert locality
  const int e = wg / 10;
  const int t0 = (wg % 10) * 64;
  const int cnt = counts_eff[e];
  if (t0 >= cnt) return;

  __shared__ int aid[64];
  __shared__ int toks[64];
  __shared__ float wts[64];
  __shared__ unsigned short Ht[64 * 128];  // 16 KB (256B-row swizzled)
  __shared__ char BUF[49152];  // ph1: 2x{At 8K + Bt 16K}; ph2: Vt dbuf 2x16K

  const int tid = threadIdx.x;
  const int lane = tid & 63, wid = tid >> 6;
  const int wr = wid >> 1, wc = wid & 1;
  const int fr = lane & 15, fq = lane >> 4;

  if (tid < 64) {
    const int i = t0 + tid;
    if (i < cnt) {
      const int a = slots[e * CAP + i];
      aid[tid] = a;
      toks[tid] = a >> 1;
      wts[tid] = wkf[a] * gamma[e];
    } else {
      aid[tid] = -1;
      toks[tid] = slots[e * CAP] >> 1;
      wts[tid] = 0.f;
    }
  }
  __syncthreads();

  // ---------- phase 1: H = silu(U_e @ enc_bf[toks]^T), BK=64, dbuf --------
  const unsigned short* Ue = Ub + (size_t)e * RRANK * DDIM;

  size_t aoff[2]; int da[2];
#pragma unroll
  for (int is = 0; is < 2; ++is) {
    const int doff = is * 4096 + tid * 16;
    const int r = doff >> 7;
    const int cs = ((doff >> 4) & 7) ^ (r & 7);
    aoff[is] = (size_t)toks[r] * DDIM + cs * 8;
    da[is] = doff;
  }
  const unsigned short* bsrc[4]; int db[4];
#pragma unroll
  for (int is = 0; is < 4; ++is) {
    const int doff = is * 4096 + tid * 16;
    const int r = doff >> 7;
    const int cs = ((doff >> 4) & 7) ^ (r & 7);
    bsrc[is] = Ue + (size_t)r * DDIM + cs * 8;
    db[is] = doff;
  }

  auto STAGE1 = [&](int buf, int kb) {  // 6 loads: 2 A + 4 B
    char* base = BUF + buf * 24576;
    gload16(encbf + aoff[0] + kb, base + da[0]);
    gload16(encbf + aoff[1] + kb, base + da[1]);
#pragma unroll
    for (int is = 0; is < 4; ++is)
      gload16(bsrc[is] + kb, base + 8192 + db[is]);
  };

  f32x4 hacc[2][4];
#pragma unroll
  for (int m = 0; m < 2; ++m)
#pragma unroll
    for (int n = 0; n < 4; ++n) hacc[m][n] = (f32x4){0.f, 0.f, 0.f, 0.f};

  STAGE1(0, 0);
  STAGE1(1, 64);
  asm volatile("s_waitcnt vmcnt(6)" ::: "memory");  // tile0 landed; tile1 in flight
  __builtin_amdgcn_s_barrier();
  asm volatile("" ::: "memory");

#pragma unroll 1
  for (int t = 0; t < 32; ++t) {
    const int cur = t & 1;
    const char* At = BUF + cur * 24576;
    const char* Bt = At + 8192;

#pragma unroll
    for (int kk = 0; kk < 2; ++kk) {
      bf16x8 af[2], bfv[4];
#pragma unroll
      for (int m = 0; m < 2; ++m) {
        const int row = wr * 32 + m * 16 + fr;
        af[m] = *(const bf16x8*)(At + row * 128 + (((kk * 4 + fq) ^ (row & 7)) << 4));
      }
#pragma unroll
      for (int n = 0; n < 4; ++n) {
        const int row = wc * 64 + n * 16 + fr;
        bfv[n] = *(const bf16x8*)(Bt + row * 128 + (((kk * 4 + fq) ^ (row & 7)) << 4));
      }
      __builtin_amdgcn_s_setprio(1);
#pragma unroll
      for (int m = 0; m < 2; ++m)
#pragma unroll
        for (int n = 0; n < 4; ++n)
          hacc[m][n] = __builtin_amdgcn_mfma_f32_16x16x32_bf16(af[m], bfv[n], hacc[m][n], 0, 0, 0);
      __builtin_amdgcn_s_setprio(0);
    }

    asm volatile("s_waitcnt lgkmcnt(0)" ::: "memory");  // reads of buf[cur] retired
    __builtin_amdgcn_s_barrier();                       // all waves done with buf[cur]
    if (t < 30) {
      STAGE1(cur, (t + 2) * 64);                        // overwrite for tile t+2
      asm volatile("s_waitcnt vmcnt(6)" ::: "memory");  // tile t+1 landed
    } else {
      asm volatile("s_waitcnt vmcnt(0)" ::: "memory");  // epilogue drain
    }
    __builtin_amdgcn_s_barrier();                       // next buffer ready
    asm volatile("" ::: "memory");
  }

  // prefetch V halves 0,1 into BUF while Ht is being written
  const unsigned short* Ve = Vb + (size_t)e * DDIM * RRANK;
  auto STAGEV = [&](int buf, int nh) {
    const unsigned short* vs = Ve + (size_t)nh * 64 * RRANK;
    char* vd = BUF + buf * 16384;
#pragma unroll
    for (int is = 0; is < 4; ++is) {
      const int d = is * 4096 + tid * 16;
      gload16(vs + (swz256(d) >> 1), vd + d);
    }
  };
  STAGEV(0, 0);
  STAGEV(1, 1);

  // write H tile to Ht LDS (swizzled, bf16) with silu
#pragma unroll
  for (int m = 0; m < 2; ++m) {
#pragma unroll
    for (int j = 0; j < 4; ++j) {
      const int row = wr * 32 + m * 16 + fq * 4 + j;
#pragma unroll
      for (int n = 0; n < 4; ++n) {
        const int col = wc * 64 + n * 16 + fr;
        const int b = (row * 256 + col * 2) ^ ((row & 7) << 4);
        *(unsigned short*)((char*)Ht + b) = f2bf(silu_f(hacc[m][n][j]));
      }
    }
  }
  asm volatile("s_waitcnt lgkmcnt(0)" ::: "memory");
  __builtin_amdgcn_s_barrier();   // Ht visible; V prefetch still in flight
  asm volatile("" ::: "memory");

  // ---------- phase 2: Dbuf = w*gamma*(H @ V_e^T), 32 x 64-row halves ------
  bf16x8 paf[2][4];
  float wv[2][4];
  int av[2][4];
#pragma unroll
  for (int m = 0; m < 2; ++m) {
    const int row = wr * 32 + m * 16 + fr;
#pragma unroll
    for (int kk = 0; kk < 4; ++kk) {
      const int b = (row * 256 + kk * 64 + fq * 16) ^ ((row & 7) << 4);
      paf[m][kk] = *(const bf16x8*)((const char*)Ht + b);
    }
#pragma unroll
    for (int j = 0; j < 4; ++j) {
      const int tl = wr * 32 + m * 16 + fq * 4 + j;
      wv[m][j] = wts[tl];
      av[m][j] = aid[tl];
    }
  }

  asm volatile("s_waitcnt vmcnt(4)" ::: "memory");  // half 0 landed
  __builtin_amdgcn_s_barrier();
  asm volatile("" ::: "memory");

#pragma unroll 1
  for (int h = 0; h < 32; ++h) {
    const char* Vh = BUF + (h & 1) * 16384;

    f32x4 acc[2][2];
#pragma unroll
    for (int m = 0; m < 2; ++m)
#pragma unroll
      for (int n = 0; n < 2; ++n) acc[m][n] = (f32x4){0.f, 0.f, 0.f, 0.f};

    __builtin_amdgcn_s_setprio(1);
#pragma unroll
    for (int n = 0; n < 2; ++n) {
      const int drl = wc * 32 + n * 16 + fr;
#pragma unroll
      for (int kk = 0; kk < 4; ++kk) {
        const int b = (drl * 256 + kk * 64 + fq * 16) ^ ((drl & 7) << 4);
        const bf16x8 bfr = *(const bf16x8*)(Vh + b);
#pragma unroll
        for (int m = 0; m < 2; ++m)
          acc[m][n] = __builtin_amdgcn_mfma_f32_16x16x32_bf16(paf[m][kk], bfr, acc[m][n], 0, 0, 0);
      }
    }
    __builtin_amdgcn_s_setprio(0);

#pragma unroll
    for (int m = 0; m < 2; ++m) {
#pragma unroll
      for (int j = 0; j < 4; ++j) {
        if (av[m][j] >= 0) {
          const float w = wv[m][j];
          unsigned short* dp = Dbuf + (size_t)av[m][j] * DDIM + h * 64 + wc * 32 + fr;
          dp[0]  = f2bf(acc[m][0][j] * w);
          dp[16] = f2bf(acc[m][1][j] * w);
        }
      }
    }

    asm volatile("s_waitcnt lgkmcnt(0)" ::: "memory");
    __builtin_amdgcn_s_barrier();           // all waves done reading Vh
    if (h < 30) {
      STAGEV(h & 1, h + 2);
      asm volatile("s_waitcnt vmcnt(4)" ::: "memory");  // half h+1 landed
    } else {
      asm volatile("s_waitcnt vmcnt(0)" ::: "memory");
    }
    __builtin_amdgcn_s_barrier();
    asm volatile("" ::: "memory");
  }
}

// -------- combine: y[t] = enc_bf[t] + Dbuf[2t] + Dbuf[2t+1] ----------------
__global__ __launch_bounds__(256) void combine_kernel(
    const unsigned short* __restrict__ encbf, const unsigned short* __restrict__ Dbuf,
    const int* __restrict__ val, float* __restrict__ y)
{
  const int t = blockIdx.x;
  const int tid = threadIdx.x;
  const int c0 = tid * 8;
  float* yp = y + (size_t)t * DDIM + c0;
  const int v0 = val[2 * t], v1 = val[2 * t + 1];

  const ushort4 e0 = *(const ushort4*)(encbf + (size_t)t * DDIM + c0);
  const ushort4 e1 = *(const ushort4*)(encbf + (size_t)t * DDIM + c0 + 4);
  float o[8] = {bf2f(e0.x), bf2f(e0.y), bf2f(e0.z), bf2f(e0.w),
                bf2f(e1.x), bf2f(e1.y), bf2f(e1.z), bf2f(e1.w)};

  if (v0) {
    const ushort4 d0 = *(const ushort4*)(Dbuf + (size_t)(2 * t) * DDIM + c0);
    const ushort4 d1 = *(const ushort4*)(Dbuf + (size_t)(2 * t) * DDIM + c0 + 4);
    o[0] += bf2f(d0.x); o[1] += bf2f(d0.y); o[2] += bf2f(d0.z); o[3] += bf2f(d0.w);
    o[4] += bf2f(d1.x); o[5] += bf2f(d1.y); o[6] += bf2f(d1.z); o[7] += bf2f(d1.w);
  }
  if (v1) {
    const ushort4 d0 = *(const ushort4*)(Dbuf + (size_t)(2 * t + 1) * DDIM + c0);
    const ushort4 d1 = *(const ushort4*)(Dbuf + (size_t)(2 * t + 1) * DDIM + c0 + 4);
    o[0] += bf2f(d0.x); o[1] += bf2f(d0.y); o[2] += bf2f(d0.z); o[3] += bf2f(d0.w);
    o[4] += bf2f(d1.x); o[5] += bf2f(d1.y); o[6] += bf2f(d1.z); o[7] += bf2f(d1.w);
  }
  *(float4*)(yp) = (float4){o[0], o[1], o[2], o[3]};
  *(float4*)(yp + 4) = (float4){o[4], o[5], o[6], o[7]};
}

extern "C" void kernel_launch(void* const* d_in, const int* in_sizes, int n_in,
                              void* d_out, int out_size, void* d_ws, size_t ws_size,
                              hipStream_t stream)
{
  const float* x     = (const float*)d_in[0];
  const float* We    = (const float*)d_in[1];
  const float* be    = (const float*)d_in[2];
  const float* Wg    = (const float*)d_in[3];
  const float* U     = (const float*)d_in[4];
  const float* V     = (const float*)d_in[5];
  const float* gamma = (const float*)d_in[6];
  float* y = (float*)d_out;

  char* ws = (char*)d_ws;
  // small persistent buffers
  int*            topk       = (int*)(ws + 0);                   // 128 KB
  float*          wkf        = (float*)(ws + 131072);            // 128 KB
  int*            counts_eff = (int*)(ws + 262144);              // 256 B
  double*         c64        = (double*)(ws + 262400);           // 512 B
  int*            cand8      = (int*)(ws + 262912);              // 512 KB
  double*         Gt         = (double*)(ws + 787200);           // 1 MB
  unsigned short* G_bf       = (unsigned short*)(ws + 1835776);  // 256 KB
  int*            slots      = (int*)(ws + 2097920);             // 160 KB
  int*            val        = (int*)(ws + 2261760);             // 128 KB
  // Dbuf region (128 MB) ALIASES {x_bf, We_bf, Gpart}: those are dead before
  // expert_fused writes Dbuf (stream-ordered), combine reads Dbuf after.
  unsigned short* Dbuf       = (unsigned short*)(ws + 2392832);  // 128 MB
  unsigned short* x_bf       = (unsigned short*)(ws + 2392832);  // 64 MB (alias)
  unsigned short* We_bf      = (unsigned short*)(ws + 69501696); // 8 MB (alias)
  double*         Gpart      = (double*)(ws + 77890304);         // 8 MB (alias)
  // long-lived bf16 weights + enc
  unsigned short* U_bf       = (unsigned short*)(ws + 136610560);// 32 MB
  unsigned short* V_bf       = (unsigned short*)(ws + 170164992);// 32 MB
  unsigned short* enc_bf     = (unsigned short*)(ws + 203719424);// 64 MB
  // total ws use ~258.3 MB

  cvt_all_kernel<<<dim3(2048), 256, 0, stream>>>(x, We, U, V, x_bf, We_bf, U_bf, V_bf, val);

  gmat_part_kernel<<<dim3(32, 8), 256, 0, stream>>>(We, Wg, Gpart);
  greduce_kernel<<<dim3(512), 256, 0, stream>>>(Gpart, Gt, G_bf);
  bias_c_kernel<<<dim3(64), 256, 0, stream>>>(be, Wg, c64);
  logits_topc_kernel<<<dim3(256), 256, 0, stream>>>(x_bf, G_bf, c64, cand8);
  refine_kernel<<<dim3(4096), 256, 0, stream>>>(x, Gt, c64, cand8, topk, wkf);
  route_kernel<<<dim3(64), 256, 0, stream>>>(topk, wkf, slots, counts_eff, val);

  enc_mfma5<<<dim3(512), 512, 0, stream>>>(x_bf, We_bf, be, enc_bf);
  expert_fused<<<dim3(640), 256, 0, stream>>>(enc_bf, U_bf, V_bf, gamma, counts_eff, slots, wkf, Dbuf);
  combine_kernel<<<dim3(NTOK), 256, 0, stream>>>(enc_bf, Dbuf, val, y);
}

// Round 18
// 655.566 us; speedup vs baseline: 1.0988x; 1.0988x over previous
//
#include <hip/hip_runtime.h>
#include <math.h>

#define NTOK 16384
#define DDIM 2048
#define NEXP 64
#define RRANK 128
#define CAP 640  // ceil(1.25 * 32768 / 64)

typedef __attribute__((ext_vector_type(8))) short bf16x8;
typedef __attribute__((ext_vector_type(4))) float f32x4;
typedef __attribute__((address_space(1))) const unsigned int gu32_t;
typedef __attribute__((address_space(3))) unsigned int lu32_t;

__device__ __forceinline__ void gload16(const void* g, void* l) {
  __builtin_amdgcn_global_load_lds((gu32_t*)g, (lu32_t*)l, 16, 0, 0);
}

__device__ __forceinline__ float silu_f(float v) {
  return v / (1.f + expf(-v));
}

__device__ __forceinline__ unsigned short f2bf(float f) {
  unsigned int u = __float_as_uint(f);
  unsigned int r = (u + 0x7fffu + ((u >> 16) & 1u)) >> 16;
  return (unsigned short)r;
}

__device__ __forceinline__ float bf2f(unsigned short u) {
  return __uint_as_float(((unsigned int)u) << 16);
}

__device__ __forceinline__ int swz256(int d) {  // XOR-swizzle for 256B-row tiles
  return d ^ (((d >> 8) & 7) << 4);
}

// ------- fp32 -> bf16 bulk convert (all 4 tensors) + val zeroing -----------
__global__ __launch_bounds__(256) void cvt_all_kernel(
    const float* __restrict__ x, const float* __restrict__ We,
    const float* __restrict__ U, const float* __restrict__ V,
    unsigned short* __restrict__ xb, unsigned short* __restrict__ Web,
    unsigned short* __restrict__ Ub, unsigned short* __restrict__ Vb,
    int* __restrict__ val)
{
  const int S0 = NTOK * DDIM / 4;
  const int S1 = DDIM * DDIM / 4;
  const int S2 = NEXP * RRANK * DDIM / 4;
  const int total = S0 + S1 + 2 * S2;
  const int g0 = blockIdx.x * 256 + threadIdx.x;
  if (g0 < NTOK * 2) val[g0] = 0;   // grid 2048*256 >= 32768
  int i = g0;
  const int stride = gridDim.x * 256;
  for (; i < total; i += stride) {
    const float* in; unsigned short* out; int j;
    if (i < S0) { in = x; out = xb; j = i; }
    else if (i < S0 + S1) { in = We; out = Web; j = i - S0; }
    else if (i < S0 + S1 + S2) { in = U; out = Ub; j = i - S0 - S1; }
    else { in = V; out = Vb; j = i - S0 - S1 - S2; }
    const float4 v = ((const float4*)in)[j];
    ushort4 o;
    o.x = f2bf(v.x); o.y = f2bf(v.y); o.z = f2bf(v.z); o.w = f2bf(v.w);
    ((ushort4*)out)[j] = o;
  }
}

// ---- encoder GEMM: 256x256 tile, BK=64, 8 waves, dbuf LDS, counted vmcnt,
//      split-phase: stage 6/8 loads after phase-A (their LDS targets dead) ---
__global__ __launch_bounds__(512, 2) void enc_mfma5(
    const unsigned short* __restrict__ xb, const unsigned short* __restrict__ Web,
    const float* __restrict__ be, unsigned short* __restrict__ encbf)
{
  __shared__ unsigned short LDS[65536];  // A0|A1|B0|B1, 32KB each (128KB)
  const int tid = threadIdx.x;
  const int lane = tid & 63, wid = tid >> 6;
  const int wr = wid >> 2, wc = wid & 3;     // 2M x 4N wave grid
  const int fr = lane & 15, fq = lane >> 4;
  const int bid = blockIdx.x;
  const int wg = (bid & 7) * 64 + (bid >> 3);  // bijective XCD swizzle (512%8==0)
  const int n0 = (wg & 7) * 256, m0 = (wg >> 3) * 256;

  const unsigned short* asb[4];
  const unsigned short* bsb[4];
  int d4[4];
#pragma unroll
  for (int is = 0; is < 4; ++is) {
    const int doff = is * 8192 + tid * 16;   // bytes within 32KB tile
    const int r = doff >> 7;                 // 128B rows (64 bf16): is*64 + tid/8
    const int cs = ((doff >> 4) & 7) ^ (r & 7);
    asb[is] = xb + (size_t)(m0 + r) * DDIM + cs * 8;
    bsb[is] = Web + (size_t)(n0 + r) * DDIM + cs * 8;
    d4[is] = doff;
  }

  auto STAGE_A = [&](int buf, int kb, int is) {
    gload16(asb[is] + kb, (char*)(LDS + buf * 16384) + d4[is]);
  };
  auto STAGE_B = [&](int buf, int kb, int is) {
    gload16(bsb[is] + kb, (char*)(LDS + 32768 + buf * 16384) + d4[is]);
  };

  f32x4 acc[8][4];
#pragma unroll
  for (int m = 0; m < 8; ++m)
#pragma unroll
    for (int n = 0; n < 4; ++n) acc[m][n] = (f32x4){0.f, 0.f, 0.f, 0.f};

  // prologue: tiles 0 and 1
#pragma unroll
  for (int is = 0; is < 4; ++is) { STAGE_A(0, 0, is); STAGE_B(0, 0, is); }
#pragma unroll
  for (int is = 0; is < 4; ++is) { STAGE_A(1, 64, is); STAGE_B(1, 64, is); }
  asm volatile("s_waitcnt vmcnt(8)" ::: "memory");  // tile0 landed; tile1 in flight
  __builtin_amdgcn_s_barrier();
  asm volatile("" ::: "memory");

#pragma unroll 1
  for (int t = 0; t < 32; ++t) {
    const int cur = t & 1;
    const int kb2 = (t + 2) * 64;
    const unsigned short* Ab = LDS + cur * 16384;
    const unsigned short* Bb = LDS + 32768 + cur * 16384;

    // ---- phase A: all B-frags + A-frags mh=0 (rows: wr=0->is0, wr=1->is2) --
    bf16x8 bfv[4][2];
#pragma unroll
    for (int n = 0; n < 4; ++n) {
      const int row = wc * 64 + n * 16 + fr;
#pragma unroll
      for (int kk = 0; kk < 2; ++kk)
        bfv[n][kk] = *(const bf16x8*)((const char*)Bb +
                      row * 128 + (((kk * 4 + fq) ^ (row & 7)) << 4));
    }
    {
      bf16x8 af[4][2];
#pragma unroll
      for (int m = 0; m < 4; ++m) {
        const int row = wr * 128 + m * 16 + fr;
#pragma unroll
        for (int kk = 0; kk < 2; ++kk)
          af[m][kk] = *(const bf16x8*)((const char*)Ab +
                       row * 128 + (((kk * 4 + fq) ^ (row & 7)) << 4));
      }
      __builtin_amdgcn_s_setprio(1);
#pragma unroll
      for (int m = 0; m < 4; ++m)
#pragma unroll
        for (int n = 0; n < 4; ++n)
#pragma unroll
          for (int kk = 0; kk < 2; ++kk)
            acc[m][n] = __builtin_amdgcn_mfma_f32_16x16x32_bf16(
                af[m][kk], bfv[n][kk], acc[m][n], 0, 0, 0);
      __builtin_amdgcn_s_setprio(0);
    }

    asm volatile("s_waitcnt lgkmcnt(0)" ::: "memory");  // phase-A reads retired
    __builtin_amdgcn_s_barrier();                       // b1: is0,is2,B dead
    if (t < 30) {  // stage 6 loads into dead regions; overlap with phase B
      STAGE_A(cur, kb2, 0);
      STAGE_A(cur, kb2, 2);
#pragma unroll
      for (int is = 0; is < 4; ++is) STAGE_B(cur, kb2, is);
    }

    // ---- phase B: A-frags mh=1 (rows: wr=0->is1, wr=1->is3) ---------------
    {
      bf16x8 af[4][2];
#pragma unroll
      for (int m = 0; m < 4; ++m) {
        const int row = wr * 128 + 64 + m * 16 + fr;
#pragma unroll
        for (int kk = 0; kk < 2; ++kk)
          af[m][kk] = *(const bf16x8*)((const char*)Ab +
                       row * 128 + (((kk * 4 + fq) ^ (row & 7)) << 4));
      }
      __builtin_amdgcn_s_setprio(1);
#pragma unroll
      for (int m = 0; m < 4; ++m)
#pragma unroll
        for (int n = 0; n < 4; ++n)
#pragma unroll
          for (int kk = 0; kk < 2; ++kk)
            acc[4 + m][n] = __builtin_amdgcn_mfma_f32_16x16x32_bf16(
                af[m][kk], bfv[n][kk], acc[4 + m][n], 0, 0, 0);
      __builtin_amdgcn_s_setprio(0);
    }

    asm volatile("s_waitcnt lgkmcnt(0)" ::: "memory");  // phase-B reads retired
    __builtin_amdgcn_s_barrier();                       // b2: is1,is3 dead
    if (t < 30) {
      STAGE_A(cur, kb2, 1);
      STAGE_A(cur, kb2, 3);
      asm volatile("s_waitcnt vmcnt(8)" ::: "memory");  // tile t+1 fully landed
    } else {
      asm volatile("s_waitcnt vmcnt(0)" ::: "memory");  // epilogue drain
    }
    __builtin_amdgcn_s_barrier();                       // b3: next buffer ready
    asm volatile("" ::: "memory");
  }

  float bias[4];
#pragma unroll
  for (int n = 0; n < 4; ++n) bias[n] = be[n0 + wc * 64 + n * 16 + fr];
#pragma unroll
  for (int m = 0; m < 8; ++m) {
#pragma unroll
    for (int j = 0; j < 4; ++j) {
      const int row = m0 + wr * 128 + m * 16 + fq * 4 + j;
      unsigned short* ob = encbf + (size_t)row * DDIM + n0 + wc * 64 + fr;
#pragma unroll
      for (int n = 0; n < 4; ++n)
        ob[n * 16] = f2bf(acc[m][n][j] + bias[n]);
    }
  }
}

// ------- G partials (fp64): Gpart[oc][e][d] over o-chunk oc ----------------
__global__ __launch_bounds__(256) void gmat_part_kernel(
    const float* __restrict__ We, const float* __restrict__ Wg,
    double* __restrict__ Gpart)
{
  __shared__ float As[64][68];  // [o][d]
  __shared__ float Bs[64][68];  // [o][e]
  const int tid = threadIdx.x;
  const int d0 = blockIdx.x * 64;
  const int oc = blockIdx.y;
  const int tx = tid & 15, ty = tid >> 4;
  const int row = tid >> 2, p = (tid & 3) * 16;

  double acc[4][4];
#pragma unroll
  for (int j = 0; j < 4; ++j)
#pragma unroll
    for (int i = 0; i < 4; ++i) acc[j][i] = 0.0;

  for (int o0 = oc * 256; o0 < oc * 256 + 256; o0 += 64) {
    float4 wv[4], gv[4];
#pragma unroll
    for (int q = 0; q < 4; ++q) {
      wv[q] = *(const float4*)(We + (size_t)(o0 + row) * DDIM + d0 + p + q * 4);
      gv[q] = *(const float4*)(Wg + (size_t)row * DDIM + o0 + p + q * 4);
    }
    __syncthreads();
#pragma unroll
    for (int q = 0; q < 4; ++q) {
      const int c = p + q * 4;
      As[row][c + 0] = wv[q].x; As[row][c + 1] = wv[q].y;
      As[row][c + 2] = wv[q].z; As[row][c + 3] = wv[q].w;
      Bs[c + 0][row] = gv[q].x; Bs[c + 1][row] = gv[q].y;
      Bs[c + 2][row] = gv[q].z; Bs[c + 3][row] = gv[q].w;
    }
    __syncthreads();
#pragma unroll 8
    for (int oo = 0; oo < 64; ++oo) {
      double a[4], b[4];
#pragma unroll
      for (int j = 0; j < 4; ++j) a[j] = (double)As[oo][ty * 4 + j];
#pragma unroll
      for (int i = 0; i < 4; ++i) b[i] = (double)Bs[oo][tx * 4 + i];
#pragma unroll
      for (int j = 0; j < 4; ++j)
#pragma unroll
        for (int i = 0; i < 4; ++i)
          acc[j][i] = fma(a[j], b[i], acc[j][i]);
    }
    __syncthreads();
  }
#pragma unroll
  for (int j = 0; j < 4; ++j)
#pragma unroll
    for (int i = 0; i < 4; ++i) {
      const int d = d0 + ty * 4 + j, e = tx * 4 + i;
      Gpart[(size_t)oc * (DDIM * NEXP) + (size_t)e * DDIM + d] = acc[j][i];
    }
}

// ------- reduce partials -> Gt (fp64) + G_bf (bf16) ------------------------
__global__ __launch_bounds__(256) void greduce_kernel(
    const double* __restrict__ Gpart, double* __restrict__ Gt,
    unsigned short* __restrict__ Gbf)
{
  const int idx = blockIdx.x * 256 + threadIdx.x;  // 131072 total
  double s = 0.0;
#pragma unroll
  for (int oc = 0; oc < 8; ++oc)
    s += Gpart[(size_t)oc * (DDIM * NEXP) + idx];
  Gt[idx] = s;
  Gbf[idx] = f2bf((float)s);
}

// ---------------- c[e] = be . Wg[e]  (fp64) --------------------------------
__global__ __launch_bounds__(256) void bias_c_kernel(
    const float* __restrict__ be, const float* __restrict__ Wg,
    double* __restrict__ c64)
{
  const int e = blockIdx.x;
  const int tid = threadIdx.x;
  double s = 0.0;
  for (int o = tid; o < DDIM; o += 256)
    s += (double)be[o] * (double)Wg[(size_t)e * DDIM + o];
  __shared__ double red[256];
  red[tid] = s;
  __syncthreads();
  for (int st = 128; st > 0; st >>= 1) {
    if (tid < st) red[tid] += red[tid + st];
    __syncthreads();
  }
  if (tid == 0) c64[e] = red[0];
}

// ---- approx logits (bf16 MFMA) + per-token top-8; 64 tok/block, grid 256 --
__global__ __launch_bounds__(256) void logits_topc_kernel(
    const unsigned short* __restrict__ xb, const unsigned short* __restrict__ Gbf,
    const double* __restrict__ c64, int* __restrict__ cand8)
{
  __shared__ unsigned short At[64 * 64];  // 8 KB: tokens x k (swizzled)
  __shared__ unsigned short Bt[64 * 64];  // 8 KB: experts x k (swizzled)
  __shared__ float Ls[64][64];            // 16 KB logits
  const int tid = threadIdx.x;
  const int lane = tid & 63, wid = tid >> 6;
  const int fr = lane & 15, fq = lane >> 4;
  const int t0 = blockIdx.x * 64;  // grid 256

  // staging: 2 issues per matrix per tile; linear LDS dest, swizzled source
  const unsigned short* asrc[2];
  const unsigned short* bsrc[2];
  int d2[2];
#pragma unroll
  for (int is = 0; is < 2; ++is) {
    const int doff = is * 4096 + tid * 16;   // bytes within 8KB tile
    const int r = doff >> 7;                 // 128B rows (64 bf16)
    const int cs = ((doff >> 4) & 7) ^ (r & 7);
    asrc[is] = xb + (size_t)(t0 + r) * DDIM + cs * 8;
    bsrc[is] = Gbf + (size_t)r * DDIM + cs * 8;
    d2[is] = doff;
  }

  f32x4 acc[4];
#pragma unroll
  for (int n = 0; n < 4; ++n) acc[n] = (f32x4){0.f, 0.f, 0.f, 0.f};

  for (int kb = 0; kb < DDIM; kb += 64) {
    __syncthreads();
#pragma unroll
    for (int is = 0; is < 2; ++is) {
      gload16(asrc[is] + kb, (char*)At + d2[is]);
      gload16(bsrc[is] + kb, (char*)Bt + d2[is]);
    }
    __syncthreads();
    const int arow = wid * 16 + fr;
    bf16x8 af[2], bfr[4][2];
#pragma unroll
    for (int kk = 0; kk < 2; ++kk)
      af[kk] = *(const bf16x8*)((const char*)At +
                arow * 128 + (((kk * 4 + fq) ^ (arow & 7)) << 4));
#pragma unroll
    for (int n = 0; n < 4; ++n) {
      const int brow = n * 16 + fr;
#pragma unroll
      for (int kk = 0; kk < 2; ++kk)
        bfr[n][kk] = *(const bf16x8*)((const char*)Bt +
                      brow * 128 + (((kk * 4 + fq) ^ (brow & 7)) << 4));
    }
#pragma unroll
    for (int n = 0; n < 4; ++n)
#pragma unroll
      for (int kk = 0; kk < 2; ++kk)
        acc[n] = __builtin_amdgcn_mfma_f32_16x16x32_bf16(af[kk], bfr[n][kk], acc[n], 0, 0, 0);
  }

#pragma unroll
  for (int j = 0; j < 4; ++j) {
    const int row = wid * 16 + fq * 4 + j;
#pragma unroll
    for (int n = 0; n < 4; ++n)
      Ls[row][n * 16 + fr] = acc[n][j];
  }
  __syncthreads();

  if (tid < 64) {
    float v8[8];
    int i8[8];
#pragma unroll
    for (int c = 0; c < 8; ++c) { v8[c] = -INFINITY; i8[c] = 0; }
    for (int e = 0; e < NEXP; ++e) {
      const float v = Ls[tid][e] + (float)c64[e];
      if (v > v8[7]) {
        int p = 7;
        while (p > 0 && v > v8[p - 1]) { v8[p] = v8[p - 1]; i8[p] = i8[p - 1]; --p; }
        v8[p] = v; i8[p] = e;
      }
    }
    int* cp = cand8 + (size_t)(t0 + tid) * 8;
#pragma unroll
    for (int c = 0; c < 8; ++c) cp[c] = i8[c];
  }
}

// ---- exact fp64 refine of 8 candidates: wave-per-token, no barriers -------
__global__ __launch_bounds__(256) void refine_kernel(
    const float* __restrict__ x, const double* __restrict__ Gt,
    const double* __restrict__ c64, const int* __restrict__ cand8,
    int* __restrict__ topk, float* __restrict__ wkf)
{
  const int tid = threadIdx.x;
  const int lane = tid & 63, w = tid >> 6;
  const int t = blockIdx.x * 4 + w;  // grid 4096, 4 tokens/block

  // x row in registers: lane holds d = 256q + 4*lane + j (j=0..3)
  float xr[32];
  const float4* xp = (const float4*)(x + (size_t)t * DDIM);
#pragma unroll
  for (int q = 0; q < 8; ++q) {
    const float4 v = xp[q * 64 + lane];
    xr[q * 4 + 0] = v.x; xr[q * 4 + 1] = v.y;
    xr[q * 4 + 2] = v.z; xr[q * 4 + 3] = v.w;
  }

  int myc[8];
#pragma unroll
  for (int c = 0; c < 8; ++c) myc[c] = cand8[(size_t)t * 8 + c];

  double s[8];
#pragma unroll
  for (int c = 0; c < 8; ++c) {
    const double* g = Gt + (size_t)myc[c] * DDIM;
    double acc = 0.0;
#pragma unroll
    for (int q = 0; q < 8; ++q) {
      const int d = q * 256 + lane * 4;
      const double2 g0 = *(const double2*)(g + d);
      const double2 g1 = *(const double2*)(g + d + 2);
      acc = fma((double)xr[q * 4 + 0], g0.x, acc);
      acc = fma((double)xr[q * 4 + 1], g0.y, acc);
      acc = fma((double)xr[q * 4 + 2], g1.x, acc);
      acc = fma((double)xr[q * 4 + 3], g1.y, acc);
    }
#pragma unroll
    for (int off = 32; off > 0; off >>= 1)
      acc += __shfl_xor(acc, off);
    s[c] = acc + c64[myc[c]];
  }

  if (lane == 0) {
    double v1 = -1e300, v2 = -1e300;
    int i1 = 0, i2 = 0;
#pragma unroll
    for (int c = 0; c < 8; ++c) {
      const double v = s[c];
      if (v > v1) { v2 = v1; i2 = i1; v1 = v; i1 = myc[c]; }
      else if (v > v2) { v2 = v; i2 = myc[c]; }
    }
    const double e2 = exp(v2 - v1);
    const double sm = 1.0 + e2 + 1e-12;
    topk[2 * t] = i1; topk[2 * t + 1] = i2;
    wkf[2 * t] = (float)(1.0 / sm);
    wkf[2 * t + 1] = (float)(e2 / sm);
  }
}

// ------- deterministic capacity routing: 2-pass wave-local scan ------------
__global__ __launch_bounds__(256) void route_kernel(
    const int* __restrict__ topk, const float* __restrict__ wkf,
    int* __restrict__ slots /* [NEXP][CAP] */, int* __restrict__ counts_eff,
    int* __restrict__ val /* [N] pre-zeroed by cvt_all */)
{
  const int e = blockIdx.x;
  const int tid = threadIdx.x;
  const int lane = tid & 63, wave = tid >> 6;
  const int base0 = wave * 8192;  // each wave owns a contiguous range
  __shared__ int wcnt[4];

  // pass 1: count matches in this wave's range (no barriers)
  int cnt = 0;
  for (int c = 0; c < 8192; c += 64) {
    const int a = base0 + c + lane;
    const bool match = (topk[a] == e) && (wkf[a] > 1e-12f);
    cnt += (int)__popcll(__ballot(match));
  }
  if (lane == 0) wcnt[wave] = cnt;
  __syncthreads();

  int run = 0;
  for (int w = 0; w < 4; ++w)
    if (w < wave) run += wcnt[w];
  const int total = wcnt[0] + wcnt[1] + wcnt[2] + wcnt[3];

  // pass 2: assign ranks in token order
  for (int c = 0; c < 8192; c += 64) {
    const int a = base0 + c + lane;
    const bool match = (topk[a] == e) && (wkf[a] > 1e-12f);
    const unsigned long long bal = __ballot(match);
    const int rank = run + (int)__popcll(bal & ((1ull << lane) - 1ull));
    if (match && rank < CAP) {
      slots[e * CAP + rank] = a;
      val[a] = 1;
    }
    run += (int)__popcll(bal);
  }
  if (tid == 0) counts_eff[e] = (total < CAP) ? total : CAP;
}

// ----- fused expert (round-16 proven version): H = silu(U_e @ enc_bf[toks])
//       in LDS; phase 2 = 64-row V halves, dbuf + counted vmcnt
__global__ __launch_bounds__(256) void expert_fused(
    const unsigned short* __restrict__ encbf, const unsigned short* __restrict__ Ub,
    const unsigned short* __restrict__ Vb, const float* __restrict__ gamma,
    const int* __restrict__ counts_eff, const int* __restrict__ slots,
    const float* __restrict__ wkf, unsigned short* __restrict__ Dbuf)
{
  const int lin = blockIdx.x;                   // 640 wgs
  const int wg = (lin & 7) * 80 + (lin >> 3);   // XCD swizzle: expert locality
  const int e = wg / 10;
  const int t0 = (wg % 10) * 64;
  const int cnt = counts_eff[e];
  if (t0 >= cnt) return;

  __shared__ int aid[64];
  __shared__ int toks[64];
  __shared__ float wts[64];
  __shared__ unsigned short Ht[64 * 128];  // 16 KB (256B-row swizzled)
  __shared__ char U2[32768];               // ph1: At 8K + Bt 16K; ph2: Vt dbuf 2x16K

  const int tid = threadIdx.x;
  const int lane = tid & 63, wid = tid >> 6;
  const int wr = wid >> 1, wc = wid & 1;
  const int fr = lane & 15, fq = lane >> 4;

  if (tid < 64) {
    const int i = t0 + tid;
    if (i < cnt) {
      const int a = slots[e * CAP + i];
      aid[tid] = a;
      toks[tid] = a >> 1;
      wts[tid] = wkf[a] * gamma[e];
    } else {
      aid[tid] = -1;
      toks[tid] = slots[e * CAP] >> 1;
      wts[tid] = 0.f;
    }
  }
  __syncthreads();

  // ---------- phase 1: H = silu(U_e @ enc_bf[toks]^T), BK=64, swizzled ----
  unsigned short* At = (unsigned short*)U2;           // 64 x 64 bf16 (8 KB)
  unsigned short* Bt = (unsigned short*)(U2 + 8192);  // 128 x 64 bf16 (16 KB)
  const unsigned short* Ue = Ub + (size_t)e * RRANK * DDIM;

  size_t aoff[2]; char* adst[2];
#pragma unroll
  for (int is = 0; is < 2; ++is) {
    const int doff = is * 4096 + tid * 16;
    const int r = doff >> 7;
    const int cs = ((doff >> 4) & 7) ^ (r & 7);
    aoff[is] = (size_t)toks[r] * DDIM + cs * 8;
    adst[is] = (char*)At + doff;
  }
  const unsigned short* bsrc[4]; char* bdst[4];
#pragma unroll
  for (int is = 0; is < 4; ++is) {
    const int doff = is * 4096 + tid * 16;
    const int r = doff >> 7;
    const int cs = ((doff >> 4) & 7) ^ (r & 7);
    bsrc[is] = Ue + (size_t)r * DDIM + cs * 8;
    bdst[is] = (char*)Bt + doff;
  }

  f32x4 hacc[2][4];
#pragma unroll
  for (int m = 0; m < 2; ++m)
#pragma unroll
    for (int n = 0; n < 4; ++n) hacc[m][n] = (f32x4){0.f, 0.f, 0.f, 0.f};

  for (int kb = 0; kb < DDIM; kb += 64) {
    __syncthreads();
    gload16(encbf + aoff[0] + kb, adst[0]);
    gload16(encbf + aoff[1] + kb, adst[1]);
#pragma unroll
    for (int is = 0; is < 4; ++is)
      gload16(bsrc[is] + kb, bdst[is]);
    __syncthreads();
#pragma unroll
    for (int kk = 0; kk < 2; ++kk) {
      bf16x8 af[2], bfv[4];
#pragma unroll
      for (int m = 0; m < 2; ++m) {
        const int row = wr * 32 + m * 16 + fr;
        af[m] = *(const bf16x8*)((const char*)At +
                 row * 128 + (((kk * 4 + fq) ^ (row & 7)) << 4));
      }
#pragma unroll
      for (int n = 0; n < 4; ++n) {
        const int row = wc * 64 + n * 16 + fr;
        bfv[n] = *(const bf16x8*)((const char*)Bt +
                  row * 128 + (((kk * 4 + fq) ^ (row & 7)) << 4));
      }
#pragma unroll
      for (int m = 0; m < 2; ++m)
#pragma unroll
        for (int n = 0; n < 4; ++n)
          hacc[m][n] = __builtin_amdgcn_mfma_f32_16x16x32_bf16(af[m], bfv[n], hacc[m][n], 0, 0, 0);
    }
  }
  __syncthreads();  // phase-1 LDS dead; also drains phase-1 loads

  // prefetch V halves 0,1 into U2 while Ht is being written
  const unsigned short* Ve = Vb + (size_t)e * DDIM * RRANK;
  auto STAGEV = [&](int buf, int nh) {
    const unsigned short* vs = Ve + (size_t)nh * 64 * RRANK;
    char* vd = U2 + buf * 16384;
#pragma unroll
    for (int is = 0; is < 4; ++is) {
      const int d = is * 4096 + tid * 16;
      gload16(vs + (swz256(d) >> 1), vd + d);
    }
  };
  STAGEV(0, 0);
  STAGEV(1, 1);

  // write H tile to Ht LDS (swizzled, bf16) with silu
#pragma unroll
  for (int m = 0; m < 2; ++m) {
#pragma unroll
    for (int j = 0; j < 4; ++j) {
      const int row = wr * 32 + m * 16 + fq * 4 + j;
#pragma unroll
      for (int n = 0; n < 4; ++n) {
        const int col = wc * 64 + n * 16 + fr;
        const int b = (row * 256 + col * 2) ^ ((row & 7) << 4);
        *(unsigned short*)((char*)Ht + b) = f2bf(silu_f(hacc[m][n][j]));
      }
    }
  }
  asm volatile("s_waitcnt lgkmcnt(0)" ::: "memory");
  __builtin_amdgcn_s_barrier();   // Ht visible; V prefetch still in flight
  asm volatile("" ::: "memory");

  // ---------- phase 2: Dbuf = w*gamma*(H @ V_e^T), 32 x 64-row halves ------
  bf16x8 paf[2][4];
  float wv[2][4];
  int av[2][4];
#pragma unroll
  for (int m = 0; m < 2; ++m) {
    const int row = wr * 32 + m * 16 + fr;
#pragma unroll
    for (int kk = 0; kk < 4; ++kk) {
      const int b = (row * 256 + kk * 64 + fq * 16) ^ ((row & 7) << 4);
      paf[m][kk] = *(const bf16x8*)((const char*)Ht + b);
    }
#pragma unroll
    for (int j = 0; j < 4; ++j) {
      const int tl = wr * 32 + m * 16 + fq * 4 + j;
      wv[m][j] = wts[tl];
      av[m][j] = aid[tl];
    }
  }

  asm volatile("s_waitcnt vmcnt(4)" ::: "memory");  // half 0 landed
  __builtin_amdgcn_s_barrier();
  asm volatile("" ::: "memory");

#pragma unroll 1
  for (int h = 0; h < 32; ++h) {
    const char* Vh = U2 + (h & 1) * 16384;

    f32x4 acc[2][2];
#pragma unroll
    for (int m = 0; m < 2; ++m)
#pragma unroll
      for (int n = 0; n < 2; ++n) acc[m][n] = (f32x4){0.f, 0.f, 0.f, 0.f};

    __builtin_amdgcn_s_setprio(1);
#pragma unroll
    for (int n = 0; n < 2; ++n) {
      const int drl = wc * 32 + n * 16 + fr;
#pragma unroll
      for (int kk = 0; kk < 4; ++kk) {
        const int b = (drl * 256 + kk * 64 + fq * 16) ^ ((drl & 7) << 4);
        const bf16x8 bfr = *(const bf16x8*)(Vh + b);
#pragma unroll
        for (int m = 0; m < 2; ++m)
          acc[m][n] = __builtin_amdgcn_mfma_f32_16x16x32_bf16(paf[m][kk], bfr, acc[m][n], 0, 0, 0);
      }
    }
    __builtin_amdgcn_s_setprio(0);

#pragma unroll
    for (int m = 0; m < 2; ++m) {
#pragma unroll
      for (int j = 0; j < 4; ++j) {
        if (av[m][j] >= 0) {
          const float w = wv[m][j];
          unsigned short* dp = Dbuf + (size_t)av[m][j] * DDIM + h * 64 + wc * 32 + fr;
          dp[0]  = f2bf(acc[m][0][j] * w);
          dp[16] = f2bf(acc[m][1][j] * w);
        }
      }
    }

    asm volatile("s_waitcnt lgkmcnt(0)" ::: "memory");
    __builtin_amdgcn_s_barrier();           // all waves done reading Vh
    if (h < 30) {
      STAGEV(h & 1, h + 2);
      asm volatile("s_waitcnt vmcnt(4)" ::: "memory");  // half h+1 landed
    } else {
      asm volatile("s_waitcnt vmcnt(0)" ::: "memory");
    }
    __builtin_amdgcn_s_barrier();
    asm volatile("" ::: "memory");
  }
}

// -------- combine: y[t] = enc_bf[t] + Dbuf[2t] + Dbuf[2t+1] ----------------
__global__ __launch_bounds__(256) void combine_kernel(
    const unsigned short* __restrict__ encbf, const unsigned short* __restrict__ Dbuf,
    const int* __restrict__ val, float* __restrict__ y)
{
  const int t = blockIdx.x;
  const int tid = threadIdx.x;
  const int c0 = tid * 8;
  float* yp = y + (size_t)t * DDIM + c0;
  const int v0 = val[2 * t], v1 = val[2 * t + 1];

  const ushort4 e0 = *(const ushort4*)(encbf + (size_t)t * DDIM + c0);
  const ushort4 e1 = *(const ushort4*)(encbf + (size_t)t * DDIM + c0 + 4);
  float o[8] = {bf2f(e0.x), bf2f(e0.y), bf2f(e0.z), bf2f(e0.w),
                bf2f(e1.x), bf2f(e1.y), bf2f(e1.z), bf2f(e1.w)};

  if (v0) {
    const ushort4 d0 = *(const ushort4*)(Dbuf + (size_t)(2 * t) * DDIM + c0);
    const ushort4 d1 = *(const ushort4*)(Dbuf + (size_t)(2 * t) * DDIM + c0 + 4);
    o[0] += bf2f(d0.x); o[1] += bf2f(d0.y); o[2] += bf2f(d0.z); o[3] += bf2f(d0.w);
    o[4] += bf2f(d1.x); o[5] += bf2f(d1.y); o[6] += bf2f(d1.z); o[7] += bf2f(d1.w);
  }
  if (v1) {
    const ushort4 d0 = *(const ushort4*)(Dbuf + (size_t)(2 * t + 1) * DDIM + c0);
    const ushort4 d1 = *(const ushort4*)(Dbuf + (size_t)(2 * t + 1) * DDIM + c0 + 4);
    o[0] += bf2f(d0.x); o[1] += bf2f(d0.y); o[2] += bf2f(d0.z); o[3] += bf2f(d0.w);
    o[4] += bf2f(d1.x); o[5] += bf2f(d1.y); o[6] += bf2f(d1.z); o[7] += bf2f(d1.w);
  }
  *(float4*)(yp) = (float4){o[0], o[1], o[2], o[3]};
  *(float4*)(yp + 4) = (float4){o[4], o[5], o[6], o[7]};
}

extern "C" void kernel_launch(void* const* d_in, const int* in_sizes, int n_in,
                              void* d_out, int out_size, void* d_ws, size_t ws_size,
                              hipStream_t stream)
{
  const float* x     = (const float*)d_in[0];
  const float* We    = (const float*)d_in[1];
  const float* be    = (const float*)d_in[2];
  const float* Wg    = (const float*)d_in[3];
  const float* U     = (const float*)d_in[4];
  const float* V     = (const float*)d_in[5];
  const float* gamma = (const float*)d_in[6];
  float* y = (float*)d_out;

  char* ws = (char*)d_ws;
  // small persistent buffers
  int*            topk       = (int*)(ws + 0);                   // 128 KB
  float*          wkf        = (float*)(ws + 131072);            // 128 KB
  int*            counts_eff = (int*)(ws + 262144);              // 256 B
  double*         c64        = (double*)(ws + 262400);           // 512 B
  int*            cand8      = (int*)(ws + 262912);              // 512 KB
  double*         Gt         = (double*)(ws + 787200);           // 1 MB
  unsigned short* G_bf       = (unsigned short*)(ws + 1835776);  // 256 KB
  int*            slots      = (int*)(ws + 2097920);             // 160 KB
  int*            val        = (int*)(ws + 2261760);             // 128 KB
  // Dbuf region (128 MB) ALIASES {x_bf, We_bf, Gpart}: those are dead before
  // expert_fused writes Dbuf (stream-ordered), combine reads Dbuf after.
  unsigned short* Dbuf       = (unsigned short*)(ws + 2392832);  // 128 MB
  unsigned short* x_bf       = (unsigned short*)(ws + 2392832);  // 64 MB (alias)
  unsigned short* We_bf      = (unsigned short*)(ws + 69501696); // 8 MB (alias)
  double*         Gpart      = (double*)(ws + 77890304);         // 8 MB (alias)
  // long-lived bf16 weights + enc
  unsigned short* U_bf       = (unsigned short*)(ws + 136610560);// 32 MB
  unsigned short* V_bf       = (unsigned short*)(ws + 170164992);// 32 MB
  unsigned short* enc_bf     = (unsigned short*)(ws + 203719424);// 64 MB
  // total ws use ~258.3 MB

  cvt_all_kernel<<<dim3(2048), 256, 0, stream>>>(x, We, U, V, x_bf, We_bf, U_bf, V_bf, val);

  gmat_part_kernel<<<dim3(32, 8), 256, 0, stream>>>(We, Wg, Gpart);
  greduce_kernel<<<dim3(512), 256, 0, stream>>>(Gpart, Gt, G_bf);
  bias_c_kernel<<<dim3(64), 256, 0, stream>>>(be, Wg, c64);
  logits_topc_kernel<<<dim3(256), 256, 0, stream>>>(x_bf, G_bf, c64, cand8);
  refine_kernel<<<dim3(4096), 256, 0, stream>>>(x, Gt, c64, cand8, topk, wkf);
  route_kernel<<<dim3(64), 256, 0, stream>>>(topk, wkf, slots, counts_eff, val);

  enc_mfma5<<<dim3(512), 512, 0, stream>>>(x_bf, We_bf, be, enc_bf);
  expert_fused<<<dim3(640), 256, 0, stream>>>(enc_bf, U_bf, V_bf, gamma, counts_eff, slots, wkf, Dbuf);
  combine_kernel<<<dim3(NTOK), 256, 0, stream>>>(enc_bf, Dbuf, val, y);
}